// Round 2
// baseline (137.613 us; speedup 1.0000x reference)
//
#include <hip/hip_runtime.h>
#include <stdint.h>

// DepthAwareConv2d: out = conv2d(x * depth, weight, pad=1) + bias
// (depth is channel-independent, so the depth-modulated im2col GEMM factors
//  into a plain 3x3 conv of xd = x*depth).
//
// R8 = R7 with the two measured bottlenecks fixed.
//  conv: wave split changed from (o-half x row) to (row wn x px-half wp).
//        Each wave computes all 128 o (t=0..7, A frags broadcast via L1) over
//        64 px (u=0..3). Halves per-CU LDS B-read traffic (was 2x duplicated
//        across wm waves; LDS BW was the cap at MfmaUtil 33%). wt2 layout is
//        unchanged: old (s,wm,t) address wm*2048+t*512 == T*512 for T=0..7.
//  prep: phase-1 LDS write was a 16-way bank-conflicted dword scatter
//        (bank=(8*lane+cp)%32). Now each thread packs 4 consecutive channel
//        pairs at one pixel -> single ds_write_b128 at s32[px*36+4g]
//        (bank starts 4*lane%32 -> uniform 8 dwords/bank, conflict-free);
//        x loads are lane-consecutive-px dwords (fully coalesced).

#define C_IN 128
#define O_OUT 256
#define HW 128
#define NB 4
#define PADW 130

#define XD_ELEMS ((size_t)NB * PADW * PADW * C_IN)
#define XD_BYTES (XD_ELEMS * 2)          // 17,305,600 B
#define WT_ELEMS ((size_t)O_OUT * C_IN * 9)
#define WT_BYTES (WT_ELEMS * 2)          // 589,824 B

typedef __attribute__((ext_vector_type(8))) short short8;  // 8 bf16 (4 VGPRs)
typedef __attribute__((ext_vector_type(4))) float f32x4;
typedef __attribute__((ext_vector_type(2))) float f32x2;
typedef __attribute__((ext_vector_type(4))) unsigned uint4v;

__device__ __forceinline__ unsigned f2bf_bits(float f) {
  unsigned u = __builtin_bit_cast(unsigned, f);
  return (u + 0x7fffu + ((u >> 16) & 1u)) >> 16;   // RNE, inputs finite
}

__device__ __forceinline__ void async_load16(const void* g, void* l) {
  __builtin_amdgcn_global_load_lds(
      (__attribute__((address_space(1))) void*)g,
      (__attribute__((address_space(3))) void*)l, 16, 0, 0);
}

// ---- prep (single dispatch): xd rows + halo + weight frag-relayout ---------
// Blocks 0..1023  : one (n,y,h) half-row (64 channels). Phase 1: each thread
//                   packs channels 8g..8g+7 at one pixel into a b128 LDS
//                   write (conflict-free). Phase 2: b128 reads + dwordx4
//                   NHWC stores (conflict-free).
// Blocks 1024..1027: zero halo rows 0 and 129 of image n.
// Blocks 1028..1091: wt2 in MFMA-A-fragment order, contiguous per (s,T):
//   gid = o0*147456 + s*4096 + T*512 + lane*8 + j   (shorts)
//   o = o0*128 + T*16 + (lane&15)
//   cc = s/9; tap = s%9; c = cc*32 + (lane>>4)*8 + j
__global__ __launch_bounds__(256) void prep_all(const float* __restrict__ x,
                                                const float* __restrict__ depth,
                                                const float* __restrict__ w,
                                                short* __restrict__ xd,
                                                short* __restrict__ wt2) {
  const int R = blockIdx.x;
  const int tid = threadIdx.x;

  if (R >= NB * HW * 2 + NB) {              // ---- weight blocks
    int gid = (R - (NB * HW * 2 + NB)) * 4608 + tid;   // 64 * 4608 = 294912
#pragma unroll
    for (int i = 0; i < 18; ++i, gid += 256) {
      const int j = gid & 7;
      const int lane = (gid >> 3) & 63;
      const int T = (gid >> 9) & 7;        // frag row-block 0..7 (o = T*16+ln)
      const int g2 = gid >> 12;
      const int s = g2 % 36;               // K-slot in conv order: cc*9 + tap
      const int o0 = g2 / 36;
      const int ln = lane & 15, q = lane >> 4;
      const int o = (o0 << 7) + (T << 4) + ln;
      const int cc = s / 9;
      const int tap = s % 9;
      const int c = (cc << 5) + (q << 3) + j;
      wt2[gid] = (short)f2bf_bits(w[((size_t)o * C_IN + c) * 9 + tap]);
    }
    return;
  }

  if (R >= NB * HW * 2) {                   // ---- halo-row zero blocks
    const int n = R - NB * HW * 2;
    uint4v* base0 = (uint4v*)(xd + (size_t)n * PADW * PADW * C_IN);
    uint4v* base1 = (uint4v*)(xd + ((size_t)n * PADW + (PADW - 1)) * PADW * C_IN);
    const uint4v z = {0u, 0u, 0u, 0u};
    const int per_row = PADW * C_IN * 2 / 16;   // 2080 uint4 per padded row
    for (int i = tid; i < per_row; i += 256) {
      base0[i] = z;
      base1[i] = z;
    }
    return;
  }

  // ---- half-row transform blocks: channels h*64..h*64+63 of row (n,y)
  // LDS layout: s32[px 0..127][36 dwords] (stride 36 keeps b128 16B-aligned;
  // cp slot 0..31 = channel pair within the 64-ch half).
  __shared__ __align__(16) unsigned s32[HW * 36];   // 18,432 B

  const int n = R >> 8;
  const int y = (R >> 1) & 127;
  const int h = R & 1;
  const int lane = tid & 63;
  const int wave = tid >> 6;

  // zero this half's 32 dwords of the two edge pixels (x=0 and x=129)
  {
    unsigned* row = (unsigned*)(xd + (size_t)(n * PADW + y + 1) * PADW * C_IN);
    if (tid < 32) row[(h << 5) + tid] = 0u;
    else if (tid < 64) row[(size_t)(PADW - 1) * 64 + (h << 5) + (tid - 32)] = 0u;
  }

  // phase 1: thread covers chunk g = wave*2+gg (channels 8g..8g+7) at pixels
  // lane and lane+64. Loads are lane-consecutive-px dwords (coalesced);
  // each (px,g) packs into one ds_write_b128 (bank-conflict-free).
  const float d0 = depth[((size_t)n * HW + y) * HW + lane];
  const float d1 = depth[((size_t)n * HW + y) * HW + 64 + lane];
  const float* xbase = x + (((size_t)(n * C_IN + (h << 6)) * HW) + y) * HW;
#pragma unroll
  for (int gg = 0; gg < 2; ++gg) {
    const int g = (wave << 1) + gg;         // chunk 0..7
    const float* xc = xbase + ((size_t)(g << 3)) * HW * HW;
#pragma unroll
    for (int ph = 0; ph < 2; ++ph) {
      const int px = (ph << 6) + lane;
      const float d = ph ? d1 : d0;
      uint4v v;
#pragma unroll
      for (int k = 0; k < 4; ++k) {
        const float a = xc[(size_t)(2 * k) * HW * HW + px];
        const float b2 = xc[(size_t)(2 * k + 1) * HW * HW + px];
        v[k] = f2bf_bits(a * d) | (f2bf_bits(b2 * d) << 16);
      }
      *(uint4v*)&s32[px * 36 + (g << 2)] = v;
    }
  }
  __syncthreads();

  // phase 2: b128 reads + dwordx4 stores (pixels 1..128, this channel half)
  unsigned* orow = (unsigned*)(xd + ((size_t)(n * PADW + y + 1) * PADW + 1) * C_IN);
#pragma unroll
  for (int i = 0; i < 4; ++i) {
    const int flat = tid + (i << 8);        // 0..1023
    const int px = flat >> 3, jj = flat & 7;
    const uint4v v = *(const uint4v*)&s32[px * 36 + (jj << 2)];
    *(uint4v*)&orow[(size_t)px * 64 + (h << 5) + (jj << 2)] = v;
  }
}

// ---- main MFMA implicit-GEMM conv ------------------------------------------
// Block: 256 threads (4 waves), tile 128(o) x 256(px = 2 output rows).
// Wave split: wn = row (0/1), wp = px-half (0/1). Each wave: ALL 128 o
// (t=0..7; A frags identical across waves -> L1 broadcast) x 64 px (u=0..3).
// This halves per-CU LDS B-read traffic vs the old 2x2 (o-half x row) split
// where both wm waves read identical B bytes (LDS BW was the bottleneck).
// K = 1152 as (cc 0..3) x (tap 0..8). Double-buffered strips; next-phase
// global_load_lds chunks spread across taps AFTER each tap's a-prefetch.
__global__ __launch_bounds__(256, 2) void conv_mfma(
    const short* __restrict__ xd, const short* __restrict__ wt2,
    const float* __restrict__ bias, float* __restrict__ out) {
  __shared__ __align__(16) short xbuf[2][16640];   // 2 x [px_strip 520][32 ch]

  const int tid = threadIdx.x;
  const int bx = blockIdx.x;            // n*64 + ypair
  const int n = bx >> 6;
  const int y = (bx & 63) << 1;         // first of two output rows
  const int o0b = blockIdx.y;           // o tile (x128)
  const int lane = tid & 63;
  const int wave = tid >> 6;
  const int wn = wave & 1;              // output row within the pair
  const int wp = wave >> 1;             // px half: 0 -> 0..63, 1 -> 64..127
  const int ln = lane & 15, q = lane >> 4;

  // W fragment stream base (shorts): frag (s,T) is a contiguous 1KB at
  // wbase + s*4096 + T*512 (identical for all 4 waves -> L1 broadcast)
  const short* wbase = wt2 + (size_t)o0b * 147456 + (lane << 3);

  // X strip staging: strip = padded rows y..y+3, px 0..129, chunk f=0..2079
  // src(f) = strip_base + (f>>2)*128 + cc*32 + (f&3)*8 ; lds(f) = f*8
  const short* xsrc0 = xd + (size_t)(n * PADW + y) * PADW * C_IN +
                       (tid >> 2) * C_IN + (tid & 3) * 8;

  f32x4 acc[8][4] = {};
  short8 areg[2][8];

  auto loadA = [&](int s, int p) {
#pragma unroll
    for (int t = 0; t < 8; ++t)
      areg[p][t] = *(const short8*)(wbase + (size_t)s * 4096 + t * 512);
  };

  {  // prologue: stage strip cc=0 into buf0
    short* xdst = &xbuf[0][0] + tid * 8;
#pragma unroll
    for (int j = 0; j < 8; ++j)
      async_load16(xsrc0 + j * 8192, xdst + j * 2048);
    if (tid < 32) async_load16(xsrc0 + 8 * 8192, xdst + 8 * 2048);
  }
  loadA(0, 0);
  __syncthreads();   // buf0 ready

#pragma unroll
  for (int cc = 0; cc < 4; ++cc) {
#pragma unroll
    for (int tap = 0; tap < 9; ++tap) {
      const int s = cc * 9 + tap;
      if (s + 1 < 36) loadA(s + 1, (s + 1) & 1);   // prefetch next a-frags

      if (cc + 1 < 4) {   // spread next-strip staging across taps (after loadA!)
        const short* sp = xsrc0 + ((cc + 1) << 5);
        short* xdst = &xbuf[(cc + 1) & 1][0] + tid * 8;
        if (tap < 8) async_load16(sp + tap * 8192, xdst + tap * 2048);
        if (tap == 0 && tid < 32)
          async_load16(sp + 8 * 8192, xdst + 8 * 2048);  // tail 32 chunks
      }

      const int ti = tap / 3, tj = tap % 3;        // static under unroll
      const int rbase = (wn + ti) * 130 + tj + (wp << 6);

      short8 b[4];
#pragma unroll
      for (int u = 0; u < 4; ++u)
        b[u] = *(const short8*)(&xbuf[cc & 1][0] +
                                (rbase + (u << 4) + ln) * 32 + (q << 3));
      __builtin_amdgcn_s_setprio(1);
#pragma unroll
      for (int t = 0; t < 8; ++t)
#pragma unroll
        for (int u = 0; u < 4; ++u)
          acc[t][u] = __builtin_amdgcn_mfma_f32_16x16x32_bf16(
              areg[s & 1][t], b[u], acc[t][u], 0, 0, 0);
      __builtin_amdgcn_s_setprio(0);
    }
    if (cc + 1 < 4) __syncthreads();   // buf(cc+1) staged+drained; buf(cc) free
  }

  // epilogue: D layout col=lane&15 (pixel), row=q*4+r (o)
  const int yrow = y + wn;
#pragma unroll
  for (int t = 0; t < 8; ++t) {
    const int ob = (o0b << 7) + (t << 4) + (q << 2);
#pragma unroll
    for (int u = 0; u < 4; ++u) {
      const int xcol = (wp << 6) + (u << 4) + ln;  // 0..127
#pragma unroll
      for (int r = 0; r < 4; ++r) {
        const int o = ob + r;
        out[(((size_t)n * O_OUT + o) * HW + yrow) * HW + xcol] =
            acc[t][u][r] + bias[o];
      }
    }
  }
}

// ---- fallback (only if ws_size is too small): naive direct conv ------------
__global__ void conv_naive(const float* __restrict__ x,
                           const float* __restrict__ depth,
                           const float* __restrict__ w,
                           const float* __restrict__ bias,
                           float* __restrict__ out) {
  const int gid = blockIdx.x * 256 + threadIdx.x;
  if (gid >= NB * O_OUT * HW * HW) return;
  const int xc = gid & 127;
  const int y = (gid >> 7) & 127;
  const int o = (gid >> 14) & 255;
  const int n = gid >> 22;
  float s = bias[o];
  for (int c = 0; c < C_IN; ++c)
    for (int i = 0; i < 3; ++i) {
      const int yy = y + i - 1;
      if (yy < 0 || yy >= HW) continue;
      for (int j = 0; j < 3; ++j) {
        const int xx = xc + j - 1;
        if (xx < 0 || xx >= HW) continue;
        s += w[((o * C_IN + c) * 3 + i) * 3 + j] *
             x[(((size_t)n * C_IN + c) * HW + yy) * HW + xx] *
             depth[((size_t)n * HW + yy) * HW + xx];
      }
    }
  out[gid] = s;
}

extern "C" void kernel_launch(void* const* d_in, const int* in_sizes, int n_in,
                              void* d_out, int out_size, void* d_ws, size_t ws_size,
                              hipStream_t stream) {
  const float* x = (const float*)d_in[0];
  const float* depth = (const float*)d_in[1];
  // d_in[2] = camera_params (unused by reference)
  const float* weight = (const float*)d_in[3];
  const float* bias = (const float*)d_in[4];
  float* out = (float*)d_out;

  const size_t need = XD_BYTES + WT_BYTES;
  if (ws_size < need) {
    conv_naive<<<(NB * O_OUT * HW * HW + 255) / 256, 256, 0, stream>>>(
        x, depth, weight, bias, out);
    return;
  }

  short* xd = (short*)d_ws;
  short* wt2 = (short*)((char*)d_ws + XD_BYTES);

  prep_all<<<NB * HW * 2 + NB + 64, 256, 0, stream>>>(x, depth, weight, xd, wt2);
  conv_mfma<<<dim3(NB * HW / 2, 2), 256, 0, stream>>>(xd, wt2, bias, out);
}

// Round 3
// 132.814 us; speedup vs baseline: 1.0361x; 1.0361x over previous
//
#include <hip/hip_runtime.h>
#include <stdint.h>

// DepthAwareConv2d: out = conv2d(x * depth, weight, pad=1) + bias
// (depth is channel-independent, so the depth-modulated im2col GEMM factors
//  into a plain 3x3 conv of xd = x*depth).
//
// R9 = R7 conv structure (wm x wn wave split — R8's split regressed: it moved
//      traffic from LDS to the slower L1 path) + LDS bank-conflict swizzle:
//  conv B-reads had exactly 8 extra conflict cycles per ds_read_b128
//      (quarter-wave lanes hit 2 of 8 bank-quads). Swizzle q' = q^((px>>1)&3)
//      (involution, q-field only). Staging keeps LDS linear (global_load_lds
//      requirement) and pre-swizzles the SOURCE address instead:
//      q_src = (tid&3)^((tid>>3)&3) — j-independent, one-line change.
//  prep row blocks reverted to the R6 version (R7 had a 16-way LDS write
//      conflict; R8 halved load width); weight blocks keep the R8
//      T-contiguous frag layout that conv's wbase addressing needs.

#define C_IN 128
#define O_OUT 256
#define HW 128
#define NB 4
#define PADW 130

#define XD_ELEMS ((size_t)NB * PADW * PADW * C_IN)
#define XD_BYTES (XD_ELEMS * 2)          // 17,305,600 B
#define WT_ELEMS ((size_t)O_OUT * C_IN * 9)
#define WT_BYTES (WT_ELEMS * 2)          // 589,824 B

typedef __attribute__((ext_vector_type(8))) short short8;  // 8 bf16 (4 VGPRs)
typedef __attribute__((ext_vector_type(4))) float f32x4;
typedef __attribute__((ext_vector_type(2))) float f32x2;
typedef __attribute__((ext_vector_type(4))) unsigned uint4v;

__device__ __forceinline__ unsigned f2bf_bits(float f) {
  unsigned u = __builtin_bit_cast(unsigned, f);
  return (u + 0x7fffu + ((u >> 16) & 1u)) >> 16;   // RNE, inputs finite
}

__device__ __forceinline__ void async_load16(const void* g, void* l) {
  __builtin_amdgcn_global_load_lds(
      (__attribute__((address_space(1))) void*)g,
      (__attribute__((address_space(3))) void*)l, 16, 0, 0);
}

// ---- prep (single dispatch): xd rows + halo + weight frag-relayout ---------
// Blocks 0..511   : one (n,y) row. Coalesced float2 reads of x, scale by
//                   depth, c-major LDS transpose, coalesced NHWC writes.
// Blocks 512..515 : zero halo rows 0 and 129 of image n.
// Blocks 516..579 : wt2 in MFMA-A-fragment order, contiguous per (s,T):
//   gid = o0*147456 + s*4096 + T*512 + lane*8 + j   (shorts)
//   o = o0*128 + T*16 + (lane&15)
//   cc = s/9; tap = s%9; c = cc*32 + (lane>>4)*8 + j
__global__ __launch_bounds__(256) void prep_all(const float* __restrict__ x,
                                                const float* __restrict__ depth,
                                                const float* __restrict__ w,
                                                short* __restrict__ xd,
                                                short* __restrict__ wt2) {
  const int R = blockIdx.x;
  const int tid = threadIdx.x;

  if (R >= NB * HW + NB) {                  // ---- weight blocks
    int gid = (R - (NB * HW + NB)) * 4608 + tid;   // 64 * 4608 = 294912
#pragma unroll
    for (int i = 0; i < 18; ++i, gid += 256) {
      const int j = gid & 7;
      const int lane = (gid >> 3) & 63;
      const int T = (gid >> 9) & 7;        // frag row-block 0..7 (o = T*16+ln)
      const int g2 = gid >> 12;
      const int s = g2 % 36;               // K-slot in conv order: cc*9 + tap
      const int o0 = g2 / 36;
      const int ln = lane & 15, q = lane >> 4;
      const int o = (o0 << 7) + (T << 4) + ln;
      const int cc = s / 9;
      const int tap = s % 9;
      const int c = (cc << 5) + (q << 3) + j;
      wt2[gid] = (short)f2bf_bits(w[((size_t)o * C_IN + c) * 9 + tap]);
    }
    return;
  }

  if (R >= NB * HW) {                       // ---- halo-row zero blocks
    const int n = R - NB * HW;
    uint4v* base0 = (uint4v*)(xd + (size_t)n * PADW * PADW * C_IN);
    uint4v* base1 = (uint4v*)(xd + ((size_t)n * PADW + (PADW - 1)) * PADW * C_IN);
    const uint4v z = {0u, 0u, 0u, 0u};
    const int per_row = PADW * C_IN * 2 / 16;   // 2080 uint4 per padded row
    for (int i = tid; i < per_row; i += 256) {
      base0[i] = z;
      base1[i] = z;
    }
    return;
  }

  // ---- row-transform blocks (R6 version)
  __shared__ short s[C_IN * PADW];   // c-major: s[c*130 + px]

  const int n = R >> 7, y = R & 127;
  const int lane = tid & 63;
  const int wave = tid >> 6;

  // zero the two edge pixels of this padded row (x=0 and x=129)
  {
    unsigned* row = (unsigned*)(xd + ((size_t)(n * PADW + y + 1) * PADW) * C_IN);
    if (tid < 64) row[tid] = 0u;                              // pixel 0
    else if (tid < 128) row[(size_t)(PADW - 1) * 64 + (tid - 64)] = 0u;  // pixel 129
  }

  // phase 1: read x (float2, coalesced), scale, dword-write to LDS (c-major)
  const f32x2 d2 = *(const f32x2*)(depth + ((size_t)n * HW + y) * HW + 2 * lane);
  const float* xrow = x + (((size_t)n * C_IN) * HW + y) * HW + 2 * lane;
  unsigned* s32 = (unsigned*)s;
#pragma unroll 8
  for (int ci = 0; ci < 32; ++ci) {
    const int c = ci * 4 + wave;
    const f32x2 v = *(const f32x2*)(xrow + (size_t)c * HW * HW);
    s32[c * 65 + lane] = f2bf_bits(v.x * d2.x) | (f2bf_bits(v.y * d2.y) << 16);
  }
  __syncthreads();

  // phase 2: coalesced NHWC write (pixels 1..128 of the padded row)
  const unsigned short* s16 = (const unsigned short*)s;
  unsigned* orow = (unsigned*)(xd + ((size_t)(n * PADW + y + 1) * PADW + 1) * C_IN);
#pragma unroll 8
  for (int i = 0; i < 32; ++i) {
    const int flat = tid + i * 256;      // 0..8191 dwords
    const int px = flat >> 6, cp = flat & 63;
    const unsigned lo = s16[(2 * cp) * PADW + px];
    const unsigned hi = s16[(2 * cp + 1) * PADW + px];
    orow[flat] = lo | (hi << 16);
  }
}

// ---- main MFMA implicit-GEMM conv ------------------------------------------
// Block: 256 threads (4 waves, 2x2), tile 128(o) x 256(px = 2 output rows).
// Wave tile 64(o) x 128(px): acc 4x8. K = 1152 as (cc 0..3) x (tap 0..8).
// Double-buffered strips; next-phase global_load_lds chunks spread across
// taps AFTER each tap's a-prefetch (FIFO vmcnt: areg waits never drain the
// stage chunks). One barrier per phase boundary.
// LDS bank swizzle: chunk (px,q) lives at q' = q ^ ((px>>1)&3). Staging keeps
// LDS writes linear and pre-swizzles the global source; B-reads apply the
// same XOR on the read address. Removes the measured 8-cyc/read conflict.
__global__ __launch_bounds__(256, 2) void conv_mfma(
    const short* __restrict__ xd, const short* __restrict__ wt2,
    const float* __restrict__ bias, float* __restrict__ out) {
  __shared__ __align__(16) short xbuf[2][16640];   // 2 x [px_strip 520][32 ch]

  const int tid = threadIdx.x;
  const int bx = blockIdx.x;            // n*64 + ypair
  const int n = bx >> 6;
  const int y = (bx & 63) << 1;         // first of two output rows
  const int o0b = blockIdx.y;           // o tile (x128)
  const int lane = tid & 63;
  const int wave = tid >> 6;
  const int wm = wave & 1, wn = wave >> 1;
  const int ln = lane & 15, q = lane >> 4;

  // W fragment stream base (shorts): frag (s,T) contiguous 1KB, T = wm*4+t
  const short* wbase = wt2 + (size_t)o0b * 147456 + (wm << 11) + (lane << 3);

  // X strip staging: LDS chunk c = tid + j*256 (linear), global source chunk
  // pre-swizzled: q_src = (tid&3) ^ ((tid>>3)&3)  (== (c&3)^((c>>3)&3) for
  // all j since j*256 keeps both fields). px term unchanged.
  const short* xsrc0 = xd + (size_t)(n * PADW + y) * PADW * C_IN +
                       (tid >> 2) * C_IN + ((tid & 3) ^ ((tid >> 3) & 3)) * 8;

  f32x4 acc[4][8] = {};
  short8 areg[2][4];

  auto loadA = [&](int s, int p) {
#pragma unroll
    for (int t = 0; t < 4; ++t)
      areg[p][t] = *(const short8*)(wbase + (size_t)s * 4096 + t * 512);
  };

  {  // prologue: stage strip cc=0 into buf0
    short* xdst = &xbuf[0][0] + tid * 8;
#pragma unroll
    for (int j = 0; j < 8; ++j)
      async_load16(xsrc0 + j * 8192, xdst + j * 2048);
    if (tid < 32) async_load16(xsrc0 + 8 * 8192, xdst + 8 * 2048);
  }
  loadA(0, 0);
  __syncthreads();   // buf0 ready

#pragma unroll
  for (int cc = 0; cc < 4; ++cc) {
#pragma unroll
    for (int tap = 0; tap < 9; ++tap) {
      const int s = cc * 9 + tap;
      if (s + 1 < 36) loadA(s + 1, (s + 1) & 1);   // prefetch next a-frags

      if (cc + 1 < 4) {   // spread next-strip staging across taps (after loadA!)
        const short* sp = xsrc0 + ((cc + 1) << 5);
        short* xdst = &xbuf[(cc + 1) & 1][0] + tid * 8;
        if (tap < 8) async_load16(sp + tap * 8192, xdst + tap * 2048);
        if (tap == 0 && tid < 32)
          async_load16(sp + 8 * 8192, xdst + 8 * 2048);  // tail 32 chunks
      }

      const int ti = tap / 3, tj = tap % 3;        // static under unroll
      const int rbase = (wn + ti) * 130 + tj;      // strip row + col shift

      short8 b[8];
#pragma unroll
      for (int u = 0; u < 8; ++u) {
        const int px = rbase + (u << 4) + ln;
        const int qx = (q ^ ((px >> 1) & 3)) << 3; // bank swizzle (q-field)
        b[u] = *(const short8*)(&xbuf[cc & 1][0] + px * 32 + qx);
      }
      __builtin_amdgcn_s_setprio(1);
#pragma unroll
      for (int t = 0; t < 4; ++t)
#pragma unroll
        for (int u = 0; u < 8; ++u)
          acc[t][u] = __builtin_amdgcn_mfma_f32_16x16x32_bf16(
              areg[s & 1][t], b[u], acc[t][u], 0, 0, 0);
      __builtin_amdgcn_s_setprio(0);
    }
    if (cc + 1 < 4) __syncthreads();   // buf(cc+1) staged+drained; buf(cc) free
  }

  // epilogue: D layout col=lane&15 (pixel), row=q*4+r (o)
  const int yrow = y + wn;
#pragma unroll
  for (int t = 0; t < 4; ++t) {
    const int ob = (o0b << 7) + (wm << 6) + (t << 4) + (q << 2);
#pragma unroll
    for (int u = 0; u < 8; ++u) {
      const int xcol = (u << 4) + ln;           // 0..127
#pragma unroll
      for (int r = 0; r < 4; ++r) {
        const int o = ob + r;
        out[(((size_t)n * O_OUT + o) * HW + yrow) * HW + xcol] =
            acc[t][u][r] + bias[o];
      }
    }
  }
}

// ---- fallback (only if ws_size is too small): naive direct conv ------------
__global__ void conv_naive(const float* __restrict__ x,
                           const float* __restrict__ depth,
                           const float* __restrict__ w,
                           const float* __restrict__ bias,
                           float* __restrict__ out) {
  const int gid = blockIdx.x * 256 + threadIdx.x;
  if (gid >= NB * O_OUT * HW * HW) return;
  const int xc = gid & 127;
  const int y = (gid >> 7) & 127;
  const int o = (gid >> 14) & 255;
  const int n = gid >> 22;
  float s = bias[o];
  for (int c = 0; c < C_IN; ++c)
    for (int i = 0; i < 3; ++i) {
      const int yy = y + i - 1;
      if (yy < 0 || yy >= HW) continue;
      for (int j = 0; j < 3; ++j) {
        const int xx = xc + j - 1;
        if (xx < 0 || xx >= HW) continue;
        s += w[((o * C_IN + c) * 3 + i) * 3 + j] *
             x[(((size_t)n * C_IN + c) * HW + yy) * HW + xx] *
             depth[((size_t)n * HW + yy) * HW + xx];
      }
    }
  out[gid] = s;
}

extern "C" void kernel_launch(void* const* d_in, const int* in_sizes, int n_in,
                              void* d_out, int out_size, void* d_ws, size_t ws_size,
                              hipStream_t stream) {
  const float* x = (const float*)d_in[0];
  const float* depth = (const float*)d_in[1];
  // d_in[2] = camera_params (unused by reference)
  const float* weight = (const float*)d_in[3];
  const float* bias = (const float*)d_in[4];
  float* out = (float*)d_out;

  const size_t need = XD_BYTES + WT_BYTES;
  if (ws_size < need) {
    conv_naive<<<(NB * O_OUT * HW * HW + 255) / 256, 256, 0, stream>>>(
        x, depth, weight, bias, out);
    return;
  }

  short* xd = (short*)d_ws;
  short* wt2 = (short*)((char*)d_ws + XD_BYTES);

  prep_all<<<NB * HW + NB + 64, 256, 0, stream>>>(x, depth, weight, xd, wt2);
  conv_mfma<<<dim3(NB * HW / 2, 2), 256, 0, stream>>>(xd, wt2, bias, out);
}